// Round 3
// baseline (3869.655 us; speedup 1.0000x reference)
//
#include <hip/hip_runtime.h>

typedef __bf16 bf16;
typedef __bf16 bf16x8 __attribute__((ext_vector_type(8)));
typedef float f32x4 __attribute__((ext_vector_type(4)));

constexpr int kB = 64;
constexpr int kS = 2048;
constexpr int kD = 1024;          // decoder size (N of main GEMM)
constexpr int kM = 1024;          // memory size  (K of main GEMM)
constexpr int kRows = kB * kS;    // 131072

__device__ __forceinline__ void async_copy16(const void* gsrc, void* ldst) {
    __builtin_amdgcn_global_load_lds(
        (const __attribute__((address_space(1))) void*)gsrc,
        (__attribute__((address_space(3))) void*)ldst, 16, 0, 0);
}

__device__ __forceinline__ float fast_tanh(float x) {
    float e = __expf(2.0f * x);
    return 1.0f - 2.0f * __builtin_amdgcn_rcpf(e + 1.0f);
}

// ---------------------------------------------------------------------------
// P1: WT[d][m] = bf16(W_mem[m][d]) — LDS-tiled transpose, coalesced both sides.
__global__ __launch_bounds__(256) void wmem_transpose_kernel(
    const float* __restrict__ Wm, bf16* __restrict__ WT) {
    __shared__ bf16 tile[64][72];            // +8 pad to spread banks
    const int d0 = (blockIdx.x & 15) * 64;
    const int m0 = (blockIdx.x >> 4) * 64;
    const int lane = threadIdx.x & 63;
    const int grp  = threadIdx.x >> 6;       // 0..3
    #pragma unroll
    for (int r = 0; r < 16; ++r) {
        const int m = m0 + grp * 16 + r;
        tile[lane][grp * 16 + r] = (bf16)Wm[m * 1024 + d0 + lane];  // coalesced read
    }
    __syncthreads();
    #pragma unroll
    for (int r = 0; r < 16; ++r) {
        const int d = d0 + grp * 16 + r;
        WT[d * 1024 + m0 + lane] = tile[grp * 16 + r][lane];        // coalesced write
    }
}

// ---------------------------------------------------------------------------
// P2: dec_feat[b][d] = sum_m dec[b][m] * W_dec[m][d]   (tiny fp32 GEMM)
__global__ __launch_bounds__(256) void dec_project_kernel(
    const float* __restrict__ dec, const float* __restrict__ Wd,
    float* __restrict__ decf) {
    const int b = blockIdx.x;
    const int d = blockIdx.y * 256 + threadIdx.x;
    const float* drow = dec + b * kD;
    float acc = 0.f;
    #pragma unroll 8
    for (int m = 0; m < kM; ++m)
        acc += drow[m] * Wd[(size_t)m * kD + d];
    decf[b * kD + d] = acc;
}

// ---------------------------------------------------------------------------
// A: fused  E = MB @ W_mem ; partial_score = sum_d tanh(E + decf) * Wv
// 128x256 tile, 512 threads / 8 waves (2x4), wave tile 64x64 (4x4 of 16x16x32).
// v3: (a) B-tile XOR swizzle (pre-swizzled global_load_lds SOURCE + swizzled
// read slot; rule both-sides-or-neither) kills the 8-way ds_read conflict;
// (b) sred aliased onto Abuf -> LDS 53248 B -> 3 blocks/CU.
constexpr int BM = 128, BN = 256, BK = 32, APAD = 40;
constexpr int NCOL = kD / BN;   // 4
constexpr int NSTEP = kM / BK;  // 32

__global__ __launch_bounds__(512, 6) void attn_scores_kernel(
    const float* __restrict__ MBank,   // [kRows, kM] fp32
    const bf16*  __restrict__ WT,      // [kD, kM]   bf16 (W_mem transposed)
    const float* __restrict__ decf,    // [kB, kD]
    const float* __restrict__ Wv,      // [kD]
    float* __restrict__ spart)         // [NCOL][kRows]
{
    __shared__ bf16 Abuf[2][BM * APAD];  // 2 x 10240 B
    __shared__ bf16 Bbuf[2][BN * BK];    // 2 x 16384 B
    float* sred = (float*)&Abuf[0][0];   // epilogue-only alias (2048 B)

    const int tid  = threadIdx.x;
    const int wave = tid >> 6;          // 0..7
    const int lane = tid & 63;
    const int ln   = lane & 15;
    const int quad = lane >> 4;

    // ---- XCD-aware remap: linear id L; XCD = L%8 (dispatch round-robin).
    const int L = blockIdx.y * NCOL + blockIdx.x;      // 0..4095
    const int jw = L >> 3;                             // 0..511
    const int rowTile = ((L & 7) << 7) + (jw >> 2);    // 0..1023
    const int colTile = jw & 3;                        // 0..3
    const int R0 = rowTile * BM;
    const int C0 = colTile * BN;
    const int batch = rowTile >> 4;     // 128 rows always inside one batch

    const int wr = (wave >> 2) * 64;    // 0 or 64
    const int wc = (wave & 3) * 64;     // 0,64,128,192

    const int arow  = tid >> 2;         // 0..127
    const int akseg = (tid & 3) * 8;    // 0,8,16,24
    const float* aptr = MBank + (size_t)(R0 + arow) * kM + akseg;

    // B staging geometry: 16 chunks of 1KB (LDS dest linear: chunk*1024+lane*16).
    // Source k-segment pre-swizzled: LDS[n][slot s] holds global kseg s^f(n),
    // f(n)=(n>>1)&3. With n=chunk*16+(lane>>2), s=lane&3: f = (lane>>3)&3.
    const int bn0  = lane >> 2;                               // row within chunk
    const int bsrc = ((lane & 3) ^ ((lane >> 3) & 3)) * 8;    // swizzled src kseg
    // Read-side slot xor for this thread's n = wc + j*16 + ln: f(n) = (ln>>1)&3
    const int rswz = (quad ^ ((ln >> 1) & 3)) * 8;

    // ---- prologue: stage tile 0 into buf 0
    {
        const float* ap = aptr;
        f32x4 v0 = *(const f32x4*)(ap + 0);
        f32x4 v1 = *(const f32x4*)(ap + 4);
        #pragma unroll
        for (int jj = 0; jj < 2; ++jj) {
            const int chunk = wave * 2 + jj;
            const int n = chunk * 16 + bn0;
            async_copy16(WT + (size_t)(C0 + n) * kM + bsrc,
                         Bbuf[0] + chunk * 512);
        }
        bf16x8 w0;
        w0[0]=(bf16)v0[0]; w0[1]=(bf16)v0[1]; w0[2]=(bf16)v0[2]; w0[3]=(bf16)v0[3];
        w0[4]=(bf16)v1[0]; w0[5]=(bf16)v1[1]; w0[6]=(bf16)v1[2]; w0[7]=(bf16)v1[3];
        *(bf16x8*)(Abuf[0] + arow * APAD + akseg) = w0;
    }
    __syncthreads();

    f32x4 acc[4][4];
    const f32x4 zero = {0.f, 0.f, 0.f, 0.f};
    #pragma unroll
    for (int i = 0; i < 4; ++i)
        #pragma unroll
        for (int j = 0; j < 4; ++j)
            acc[i][j] = zero;

    #pragma unroll 2
    for (int t = 0; t < NSTEP; ++t) {
        const int cur = t & 1, nxt = cur ^ 1;
        const bool pf = (t + 1 < NSTEP);
        const int k1 = (t + 1) * BK;

        // ---- issue next tile's loads FIRST (A regs, then B gll) so global
        //      latency hides under the ds_read+MFMA phase below
        f32x4 v0, v1;
        if (pf) {
            const float* ap = aptr + k1;
            v0 = *(const f32x4*)(ap + 0);
            v1 = *(const f32x4*)(ap + 4);
            #pragma unroll
            for (int jj = 0; jj < 2; ++jj) {
                const int chunk = wave * 2 + jj;
                const int n = chunk * 16 + bn0;
                async_copy16(WT + (size_t)(C0 + n) * kM + k1 + bsrc,
                             Bbuf[nxt] + chunk * 512);
            }
        }

        // ---- compute current tile: 8 ds_read_b128 + 16 MFMA per wave
        const bf16* Ac = Abuf[cur];
        const bf16* Bc = Bbuf[cur];
        bf16x8 af[4], bfr[4];
        #pragma unroll
        for (int i = 0; i < 4; ++i)
            af[i] = *(const bf16x8*)(Ac + (wr + i * 16 + ln) * APAD + quad * 8);
        #pragma unroll
        for (int j = 0; j < 4; ++j)
            bfr[j] = *(const bf16x8*)(Bc + (wc + j * 16 + ln) * BK + rswz);
        __builtin_amdgcn_s_setprio(1);
        #pragma unroll
        for (int i = 0; i < 4; ++i)
            #pragma unroll
            for (int j = 0; j < 4; ++j)
                acc[i][j] = __builtin_amdgcn_mfma_f32_16x16x32_bf16(
                    af[i], bfr[j], acc[i][j], 0, 0, 0);
        __builtin_amdgcn_s_setprio(0);

        // ---- finish A prefetch: cvt + ds_write into the other buffer
        if (pf) {
            bf16x8 w0;
            w0[0]=(bf16)v0[0]; w0[1]=(bf16)v0[1]; w0[2]=(bf16)v0[2]; w0[3]=(bf16)v0[3];
            w0[4]=(bf16)v1[0]; w0[5]=(bf16)v1[1]; w0[6]=(bf16)v1[2]; w0[7]=(bf16)v1[3];
            *(bf16x8*)(Abuf[nxt] + arow * APAD + akseg) = w0;
        }
        __syncthreads();   // single barrier per K-step
    }

    // ---- epilogue: tanh(E+decf)*Wv, reduce over this block's 256 cols
    float wv[4], df[4];
    #pragma unroll
    for (int j = 0; j < 4; ++j) {
        const int d = C0 + wc + j * 16 + ln;
        wv[j] = Wv[d];
        df[j] = decf[batch * kD + d];
    }
    float rp[4][4];
    #pragma unroll
    for (int i = 0; i < 4; ++i) {
        #pragma unroll
        for (int r = 0; r < 4; ++r) {
            float p = 0.f;
            #pragma unroll
            for (int j = 0; j < 4; ++j) {
                float x = acc[i][j][r] + df[j];   // C/D: row=quad*4+r, col=ln
                p += fast_tanh(x) * wv[j];
            }
            #pragma unroll
            for (int off = 1; off < 16; off <<= 1)
                p += __shfl_xor(p, off, 64);      // sum over 16 cols in the quad
            rp[i][r] = p;
        }
    }
    if (ln == 0) {
        #pragma unroll
        for (int i = 0; i < 4; ++i)
            #pragma unroll
            for (int r = 0; r < 4; ++r)
                sred[(wr + i * 16 + quad * 4 + r) * 4 + (wave & 3)] = rp[i][r];
    }
    __syncthreads();
    if (tid < BM)
        spart[(size_t)colTile * kRows + R0 + tid] =
            (sred[tid * 4 + 0] + sred[tid * 4 + 1]) +
            (sred[tid * 4 + 2] + sred[tid * 4 + 3]);
}

// ---------------------------------------------------------------------------
// B: softmax over S per batch; writes attn_dist (fp32) to d_out+65536
__global__ __launch_bounds__(256) void softmax_kernel(
    const float* __restrict__ spart, const int* __restrict__ mask,
    float* __restrict__ attn) {
    const int b = blockIdx.x;
    const int tid = threadIdx.x;
    __shared__ float sc[kS];
    __shared__ float redm[4], reds[4];

    float lmax = -INFINITY;
    for (int s = tid; s < kS; s += 256) {
        float v = 0.f;
        #pragma unroll
        for (int t = 0; t < NCOL; ++t) v += spart[(size_t)t * kRows + b * kS + s];
        if (mask[b * kS + s] == 0) v = -INFINITY;
        sc[s] = v;
        lmax = fmaxf(lmax, v);
    }
    #pragma unroll
    for (int off = 32; off; off >>= 1) lmax = fmaxf(lmax, __shfl_xor(lmax, off, 64));
    if ((tid & 63) == 0) redm[tid >> 6] = lmax;
    __syncthreads();
    const float bmax = fmaxf(fmaxf(redm[0], redm[1]), fmaxf(redm[2], redm[3]));

    float lsum = 0.f;
    for (int s = tid; s < kS; s += 256) {
        float e = __expf(sc[s] - bmax);
        sc[s] = e;
        lsum += e;
    }
    #pragma unroll
    for (int off = 32; off; off >>= 1) lsum += __shfl_xor(lsum, off, 64);
    if ((tid & 63) == 0) reds[tid >> 6] = lsum;
    __syncthreads();
    const float inv = 1.0f / (reds[0] + reds[1] + reds[2] + reds[3]);
    for (int s = tid; s < kS; s += 256) attn[b * kS + s] = sc[s] * inv;
}

// ---------------------------------------------------------------------------
// C1: context partials. v3: 8 chunks of 256 s (longer streams, 512 blocks),
// 4 independent accumulator chains, 8 loads in flight per thread.
constexpr int NSC = 8;                   // s-chunks per batch
constexpr int SCL = kS / NSC;            // 256 s per chunk

__global__ __launch_bounds__(256) void ctx_partial_kernel(
    const float* __restrict__ MBank, const float* __restrict__ attn,
    float* __restrict__ cpart) {
    const int b  = blockIdx.x;   // 64
    const int sc = blockIdx.y;   // 0..7
    const int m4 = threadIdx.x * 4;
    const float* base = MBank + ((size_t)b * kS + sc * SCL) * kM + m4;
    const float* ap = attn + b * kS + sc * SCL;
    f32x4 a0 = {0,0,0,0}, a1 = {0,0,0,0}, a2 = {0,0,0,0}, a3 = {0,0,0,0};
    #pragma unroll 2
    for (int s = 0; s < SCL; s += 4) {
        const float c0 = ap[s], c1 = ap[s+1], c2 = ap[s+2], c3 = ap[s+3];
        f32x4 u0 = *(const f32x4*)(base + (size_t)(s+0) * kM);
        f32x4 u1 = *(const f32x4*)(base + (size_t)(s+1) * kM);
        f32x4 u2 = *(const f32x4*)(base + (size_t)(s+2) * kM);
        f32x4 u3 = *(const f32x4*)(base + (size_t)(s+3) * kM);
        a0 += u0 * c0; a1 += u1 * c1; a2 += u2 * c2; a3 += u3 * c3;
    }
    f32x4 r = (a0 + a1) + (a2 + a3);
    *(f32x4*)&cpart[((size_t)(b * NSC + sc)) * kM + m4] = r;
}

// C2: reduce the s-chunk partials -> context
__global__ __launch_bounds__(256) void ctx_reduce_kernel(
    const float* __restrict__ cpart, float* __restrict__ out) {
    const int idx = blockIdx.x * 256 + threadIdx.x;  // 65536
    const int b = idx >> 10, m = idx & 1023;
    float v = 0.f;
    #pragma unroll
    for (int c = 0; c < NSC; ++c) v += cpart[(size_t)((b * NSC + c) << 10) + m];
    out[idx] = v;
}

// ---------------------------------------------------------------------------
extern "C" void kernel_launch(void* const* d_in, const int* in_sizes, int n_in,
                              void* d_out, int out_size, void* d_ws, size_t ws_size,
                              hipStream_t stream) {
    const float* dec   = (const float*)d_in[0];   // [64,1024]
    const float* MBank = (const float*)d_in[1];   // [64,2048,1024]
    const int*   mask  = (const int*)d_in[2];     // [64,2048]
    const float* Wv    = (const float*)d_in[3];   // [1024]
    const float* Wdec  = (const float*)d_in[4];   // [1024,1024]
    const float* Wmem  = (const float*)d_in[5];   // [1024,1024]

    float* out_ctx  = (float*)d_out;              // 65536 floats
    float* out_attn = (float*)d_out + kB * kD;    // 131072 floats

    char* ws = (char*)d_ws;
    bf16*  WT    = (bf16*)ws;                                   // 2 MB
    float* decf  = (float*)(ws + (1 << 21));                    // 256 KB
    float* spart = (float*)(ws + (1 << 21) + (1 << 18));        // 2 MB (4 slices)
    float* cpart = (float*)(ws + (1 << 21) + (1 << 18) + (1 << 21)); // 2 MB (8 slices)

    wmem_transpose_kernel<<<256, 256, 0, stream>>>(Wmem, WT);
    dec_project_kernel<<<dim3(64, 4), 256, 0, stream>>>(dec, Wdec, decf);
    attn_scores_kernel<<<dim3(NCOL, 1024), 512, 0, stream>>>(MBank, WT, decf, Wv, spart);
    softmax_kernel<<<64, 256, 0, stream>>>(spart, mask, out_attn);
    ctx_partial_kernel<<<dim3(64, NSC), 256, 0, stream>>>(MBank, out_attn, cpart);
    ctx_reduce_kernel<<<256, 256, 0, stream>>>(cpart, out_ctx);
}